// Round 6
// baseline (87.694 us; speedup 1.0000x reference)
//
#include <hip/hip_runtime.h>
#include <math.h>

#define NB   16384
#define SEQ  10
#define DIM  8
#define TRIL 36

__device__ __forceinline__ constexpr int tri(int r, int c) { return r * (r + 1) / 2 + c; } // r >= c

// ---- intra-octet cross-lane: DPP quad perms (1-cycle VALU) + ds_swizzle xor masks ----
template <int CTRL>
__device__ __forceinline__ float fperm(float v) {
    return __int_as_float(__builtin_amdgcn_mov_dpp(__float_as_int(v), CTRL, 0xf, 0xf, true));
}
template <int CTRL>
__device__ __forceinline__ double dperm(double v) {
    long long u = __double_as_longlong(v);
    int lo = (int)(u & 0xffffffffLL);
    int hi = (int)(((unsigned long long)u) >> 32);
    lo = __builtin_amdgcn_mov_dpp(lo, CTRL, 0xf, 0xf, true);
    hi = __builtin_amdgcn_mov_dpp(hi, CTRL, 0xf, 0xf, true);
    return __longlong_as_double(((long long)hi << 32) | (long long)(unsigned)lo);
}
// quad perms: xor1=0xB1, xor2=0x4E, xor3=0x1B; ds_swizzle BitMode offset=(xor<<10)|0x1F
__device__ __forceinline__ float fswz4(float v) {
    return __int_as_float(__builtin_amdgcn_ds_swizzle(__float_as_int(v), 0x101F));
}
__device__ __forceinline__ double dswz4(double v) {
    long long u = __double_as_longlong(v);
    int lo = (int)(u & 0xffffffffLL);
    int hi = (int)(((unsigned long long)u) >> 32);
    lo = __builtin_amdgcn_ds_swizzle(lo, 0x101F);
    hi = __builtin_amdgcn_ds_swizzle(hi, 0x101F);
    return __longlong_as_double(((long long)hi << 32) | (long long)(unsigned)lo);
}

// ---- fp64 rsqrt/rcp: HW seed (>=2^-14) + ONE Newton -> >=2^-28 relative.
// All uses are relative-error paths (chol backward error, normalizations, final sqrt):
// delta_lambda <= ~1e-8 absolute -> delta_f <= ~5e-6, far under threshold.
__device__ __forceinline__ double rsqrt1(double x) {
    double r = __builtin_amdgcn_rsq(x);
    return r * (1.5 - 0.5 * x * r * r);
}
__device__ __forceinline__ double rcp1(double x) {
    double r = __builtin_amdgcn_rcp(x);
    return r * (2.0 - x * r);
}
__device__ __forceinline__ double sqrt1(double x) { return x * rsqrt1(x); }

// 144B embedding row = 9 aligned float4
__device__ __forceinline__ void load_row(const float* __restrict__ emb, int tok, float (&F)[TRIL]) {
    const float4* q = (const float4*)(emb + (size_t)tok * TRIL);
    #pragma unroll
    for (int i = 0; i < 9; ++i) {
        float4 v = q[i];
        F[4*i+0] = v.x; F[4*i+1] = v.y; F[4*i+2] = v.z; F[4*i+3] = v.w;
    }
}

// density = (L L^T + 2e-6 I) / (||L||_F^2 + 1.6e-5 + 1e-6), diag(L) clamped >= 1e-4 in fp32.
// fp64 products/sums: density errors perturb eigenvalues ABSOLUTELY (500x amplified at small
// lambda through sqrt(lambda+1e-6)), so this stage stays fp64.
template <bool ACCUM>
__device__ __forceinline__ void density_from(float (&Lf)[TRIL], double (&dst)[TRIL]) {
    #pragma unroll
    for (int d = 0; d < DIM; ++d) Lf[tri(d, d)] = fmaxf(Lf[tri(d, d)], 1.0e-4f);
    double tr = 1.6e-5;
    #pragma unroll
    for (int i = 0; i < TRIL; ++i) { double v = (double)Lf[i]; tr += v * v; }
    double inv = rcp1(tr + 1.0e-6);
    #pragma unroll
    for (int i = 0; i < DIM; ++i) {
        #pragma unroll
        for (int j = 0; j <= i; ++j) {
            double sum = (i == j) ? 2.0e-6 : 0.0;
            #pragma unroll
            for (int k = 0; k <= j; ++k) sum += (double)Lf[tri(i, k)] * (double)Lf[tri(j, k)];
            if (ACCUM) dst[tri(i, j)] += sum * inv;
            else       dst[tri(i, j)]  = sum * inv;
        }
    }
}

// in-place fp64 Cholesky (lower-sym 36), 1-Newton rsqrt per level
__device__ __forceinline__ void chol36(double (&M)[TRIL]) {
    #pragma unroll
    for (int j = 0; j < DIM; ++j) {
        double d = M[tri(j, j)];
        #pragma unroll
        for (int k = 0; k < j; ++k) d -= M[tri(j, k)] * M[tri(j, k)];
        d = fmax(d, 1.0e-30);
        double invd = rsqrt1(d);
        M[tri(j, j)] = d * invd;
        #pragma unroll
        for (int i = j + 1; i < DIM; ++i) {
            double v = M[tri(i, j)];
            #pragma unroll
            for (int k = 0; k < j; ++k) v -= M[tri(i, k)] * M[tri(j, k)];
            M[tri(i, j)] = v * invd;
        }
    }
}

// one XOR-pairing Jacobi round: partner = lane ^ M. tau from local view gives exactly
// opposite s / identical c on partners => symmetric branch-free update own'=c*own-s*recv.
template <int M>
__device__ __forceinline__ float jrecv(float v) {
    if constexpr (M == 1) return fperm<0xB1>(v);
    else if constexpr (M == 2) return fperm<0x4E>(v);
    else if constexpr (M == 3) return fperm<0x1B>(v);
    else return __int_as_float(__builtin_amdgcn_ds_swizzle(__float_as_int(v), (M << 10) | 0x1F));
}
template <int M>
__device__ __forceinline__ void jround(float (&o)[DIM], bool& conv) {
    float r[DIM];
    #pragma unroll
    for (int k = 0; k < DIM; ++k) r[k] = jrecv<M>(o[k]);
    float xo = 0.0f, xr = 0.0f, z = 0.0f;
    #pragma unroll
    for (int k = 0; k < DIM; ++k) {
        xo = fmaf(o[k], o[k], xo);
        xr = fmaf(r[k], r[k], xr);
        z  = fmaf(o[k], r[k], z);
    }
    float z2 = z * z;
    float d  = xr - xo;
    if (z2 > 1.0e-12f * xo * xr && z2 > 1.0e-12f * d * d) conv = false;
    if (z2 > 1.0e-16f * xo * xr) {   // skip pure-noise rotations; guards rcp(0)
        float tau = d * (0.5f * __builtin_amdgcn_rcpf(z));
        float t = __builtin_amdgcn_rcpf(fabsf(tau) + sqrtf(fmaf(tau, tau, 1.0f)));
        t = (tau >= 0.0f) ? t : -t;
        float c = __builtin_amdgcn_rsqf(fmaf(t, t, 1.0f));
        float s = t * c;
        #pragma unroll
        for (int k = 0; k < DIM; ++k) o[k] = fmaf(c, o[k], -s * r[k]);
    }
}

// 8 lanes per element: lane h owns G column h. Live-set kept < 256 VGPR (no spills at
// 2 waves/SIMD): no Rm/Lw_ copies — column-wise w exchange + one Lc broadcast.
__global__ void __launch_bounds__(256, 2)
qcbow_kernel(const int* __restrict__ contexts,  // [NB, SEQ]
             const int* __restrict__ targets,   // [NB]
             const float* __restrict__ emb,     // [100000, TRIL]
             float* __restrict__ out)           // [NB]
{
    const int tid = blockIdx.x * 256 + threadIdx.x;
    const int b = tid >> 3;
    const int h = threadIdx.x & 7;
    const bool q0 = (h < 4);

    // ---- token assignment: lane h -> ctx s=h; lanes 0,1 also ctx s=8,9; lanes 4-7 sigma
    const int base = b * SEQ;
    int tok1 = contexts[base + h];
    int tok2 = 0;                               // lanes 2,3: dummy row 0 (valid memory)
    if (h < 2)  tok2 = contexts[base + 8 + h];
    if (h >= 4) tok2 = targets[b];

    float F1[TRIL], F2[TRIL];                   // both rows loaded up-front (latency overlap)
    load_row(emb, tok1, F1);
    load_row(emb, tok2, F2);

    double A[TRIL];
    #pragma unroll
    for (int i = 0; i < TRIL; ++i) A[i] = 0.0;
    float cntf = 0.0f;

    if (tok1 != 0) { density_from<true>(F1, A); cntf = 1.0f; }
    double T[TRIL];                             // sigma on lanes 4-7; extra-ctx on lanes 0,1
    density_from<false>(F2, T);
    if (h < 2 && tok2 != 0) {
        #pragma unroll
        for (int i = 0; i < TRIL; ++i) A[i] += T[i];
        cntf += 1.0f;
    }

    // ---- allreduce A,cnt over octet ----
    #pragma unroll
    for (int i = 0; i < TRIL; ++i) A[i] += dperm<0xB1>(A[i]);
    cntf += fperm<0xB1>(cntf);
    #pragma unroll
    for (int i = 0; i < TRIL; ++i) A[i] += dperm<0x4E>(A[i]);
    cntf += fperm<0x4E>(cntf);
    #pragma unroll
    for (int i = 0; i < TRIL; ++i) A[i] += dswz4(A[i]);
    cntf += fswz4(cntf);

    double invc = rcp1((double)cntf);
    #pragma unroll
    for (int i = 0; i < TRIL; ++i) A[i] *= invc;
    #pragma unroll
    for (int d = 0; d < DIM; ++d) A[tri(d, d)] += 1.0e-6;   // rho_ctx + eps I = sqrt_rho^2

    // ---- ONE chol per lane: quad0 chols rho_ctx (A), quad1 chols sigma (T) ----
    double M[TRIL];
    #pragma unroll
    for (int i = 0; i < TRIL; ++i) M[i] = q0 ? A[i] : T[i];   // A,T die here
    chol36(M);

    // ---- w = Lw[:,h]: quad1 muxes own column (h) locally and SENDS column h-4
    // (8 doubles) to its quad0 partner. Only 16 swizzle ops; no Lw array.
    const bool h1 = (h & 1), h2 = (h & 2);
    double w[DIM];
    #pragma unroll
    for (int k = 0; k < DIM; ++k) {
        // E(J) = (k>=J) ? M[tri(k,J)] : 0 — folds at compile time per (k,J)
        #define E(J) ((k >= (J)) ? M[tri((k >= (J)) ? k : (J), (J))] : 0.0)
        double o0 = h1 ? E(5) : E(4);
        double o1 = h1 ? E(7) : E(6);
        double own = h2 ? o1 : o0;              // Lw[:,h]      (valid on quad1)
        double s0 = h1 ? E(1) : E(0);
        double s1 = h1 ? E(3) : E(2);
        double snd = h2 ? s1 : s0;              // Lw[:,h-4]    (valid on quad1)
        #undef E
        double sw = dswz4(snd);                 // quad0 receives Lw[:,h]
        w[k] = q0 ? sw : own;
    }

    // ---- Lc broadcast quad0 -> quad1 (72 swizzles), then one-shot select ----
    double Lx[TRIL];
    #pragma unroll
    for (int i = 0; i < TRIL; ++i) Lx[i] = dswz4(M[i]);
    double Lc[TRIL];
    #pragma unroll
    for (int i = 0; i < TRIL; ++i) Lc[i] = q0 ? M[i] : Lx[i];  // M,Lx die here

    // ---- G[:,h] = Lc^T * w ; eig((rho+epsI) sigma) = sing(G)^2 = final col norms^2
    float col[DIM];
    #pragma unroll
    for (int i = 0; i < DIM; ++i) {
        double s = 0.0;
        #pragma unroll
        for (int k = i; k < DIM; ++k) s += Lc[tri(k, i)] * w[k];  // w[k]=0 for k<h: W triangle
        col[i] = (float)s;
    }

    // ---- 8-processor one-sided Jacobi, XOR pairing: 7 rounds/sweep = all 28 pairs ----
    for (int sweep = 0; sweep < 8; ++sweep) {
        bool conv = true;
        jround<1>(col, conv);
        jround<2>(col, conv);
        jround<3>(col, conv);
        jround<4>(col, conv);
        jround<5>(col, conv);
        jround<6>(col, conv);
        jround<7>(col, conv);
        if (sweep >= 2 && __all(conv)) break;   // wave-uniform exit
    }

    // ---- lambda_h = ||col||^2 ; f = sum_h sqrt(lambda+1e-6) over octet ----
    double xn = 0.0;
    #pragma unroll
    for (int k = 0; k < DIM; ++k) xn += (double)col[k] * (double)col[k];
    double fp = sqrt1(xn + 1.0e-6);
    fp += dperm<0xB1>(fp);
    fp += dperm<0x4E>(fp);
    fp += dswz4(fp);
    if (h == 0) {
        double f = fmin(fp, 1.0);
        f = fmax(f, 1.0e-8);
        out[b] = (float)(-log(f));
    }
}

extern "C" void kernel_launch(void* const* d_in, const int* in_sizes, int n_in,
                              void* d_out, int out_size, void* d_ws, size_t ws_size,
                              hipStream_t stream) {
    const int*   contexts = (const int*)d_in[0];
    const int*   targets  = (const int*)d_in[1];
    const float* emb      = (const float*)d_in[2];
    float*       out      = (float*)d_out;

    qcbow_kernel<<<dim3(NB * 8 / 256), dim3(256), 0, stream>>>(contexts, targets, emb, out);
}

// Round 7
// 87.320 us; speedup vs baseline: 1.0043x; 1.0043x over previous
//
#include <hip/hip_runtime.h>
#include <math.h>

#define NB   16384
#define SEQ  10
#define DIM  8
#define TRIL 36

__device__ __forceinline__ constexpr int tri(int r, int c) { return r * (r + 1) / 2 + c; } // r >= c

// ---- DPP cross-lane within each 8-lane group (pure VALU, no LDS) ----
// quad_perm ctrls: xor1=0xB1, xor2=0x4E, xor3=0x1B. ROW_HALF_MIRROR=0x141 swaps
// lane i <-> 7-i within each 8-lane half-row, and 7-i == i^7 for 3-bit i => xor7.
// Compositions give xor4..xor6: xor4=xor3.xor7, xor5=xor2.xor7, xor6=xor1.xor7.
template <int CTRL>
__device__ __forceinline__ float fperm(float v) {
    return __int_as_float(__builtin_amdgcn_mov_dpp(__float_as_int(v), CTRL, 0xf, 0xf, true));
}
template <int CTRL>
__device__ __forceinline__ double dperm(double v) {
    long long u = __double_as_longlong(v);
    int lo = (int)(u & 0xffffffffLL);
    int hi = (int)(((unsigned long long)u) >> 32);
    lo = __builtin_amdgcn_mov_dpp(lo, CTRL, 0xf, 0xf, true);
    hi = __builtin_amdgcn_mov_dpp(hi, CTRL, 0xf, 0xf, true);
    return __longlong_as_double(((long long)hi << 32) | (long long)(unsigned)lo);
}

// ---- fp64 rsqrt/rcp: HW seed (>=2^-14) + ONE Newton -> >=2^-28 relative.
// All uses are relative-error paths (chol backward error, normalizations, final sqrt).
__device__ __forceinline__ double rsqrt1(double x) {
    double r = __builtin_amdgcn_rsq(x);
    return r * (1.5 - 0.5 * x * r * r);
}
__device__ __forceinline__ double rcp1(double x) {
    double r = __builtin_amdgcn_rcp(x);
    return r * (2.0 - x * r);
}
__device__ __forceinline__ double sqrt1(double x) { return x * rsqrt1(x); }

// 144B embedding row = 9 aligned float4
__device__ __forceinline__ void load_row(const float* __restrict__ emb, int tok, float (&F)[TRIL]) {
    const float4* q = (const float4*)(emb + (size_t)tok * TRIL);
    #pragma unroll
    for (int i = 0; i < 9; ++i) {
        float4 v = q[i];
        F[4*i+0] = v.x; F[4*i+1] = v.y; F[4*i+2] = v.z; F[4*i+3] = v.w;
    }
}

// density = (L L^T + 2e-6 I) / (||L||_F^2 + 1.6e-5 + 1e-6), diag(L) clamped >= 1e-4 in fp32.
// fp64 products/sums: density errors perturb eigenvalues ABSOLUTELY (up to ~500x amplified
// through sqrt(lambda+1e-6)), so this stage stays fp64. Trace via 4-way partial tree.
template <bool ACCUM>
__device__ __forceinline__ void density_from(float (&Lf)[TRIL], double (&dst)[TRIL]) {
    #pragma unroll
    for (int d = 0; d < DIM; ++d) Lf[tri(d, d)] = fmaxf(Lf[tri(d, d)], 1.0e-4f);
    double t0 = 0.0, t1 = 0.0, t2 = 0.0, t3 = 0.0;
    #pragma unroll
    for (int i = 0; i < 36; i += 4) {
        double v0 = (double)Lf[i],   v1 = (double)Lf[i+1];
        double v2 = (double)Lf[i+2], v3 = (double)Lf[i+3];
        t0 += v0 * v0; t1 += v1 * v1; t2 += v2 * v2; t3 += v3 * v3;
    }
    double tr = ((t0 + t1) + (t2 + t3)) + 1.6e-5;
    double inv = rcp1(tr + 1.0e-6);
    #pragma unroll
    for (int i = 0; i < DIM; ++i) {
        #pragma unroll
        for (int j = 0; j <= i; ++j) {
            double sum = (i == j) ? 2.0e-6 : 0.0;
            #pragma unroll
            for (int k = 0; k <= j; ++k) sum += (double)Lf[tri(i, k)] * (double)Lf[tri(j, k)];
            if (ACCUM) dst[tri(i, j)] += sum * inv;
            else       dst[tri(i, j)]  = sum * inv;
        }
    }
}

// in-place fp64 Cholesky (lower-sym 36), 1-Newton rsqrt per level
__device__ __forceinline__ void chol36(double (&M)[TRIL]) {
    #pragma unroll
    for (int j = 0; j < DIM; ++j) {
        double d = M[tri(j, j)];
        #pragma unroll
        for (int k = 0; k < j; ++k) d -= M[tri(j, k)] * M[tri(j, k)];
        d = fmax(d, 1.0e-30);
        double invd = rsqrt1(d);
        M[tri(j, j)] = d * invd;
        #pragma unroll
        for (int i = j + 1; i < DIM; ++i) {
            double v = M[tri(i, j)];
            #pragma unroll
            for (int k = 0; k < j; ++k) v -= M[tri(i, k)] * M[tri(j, k)];
            M[tri(i, j)] = v * invd;
        }
    }
}

// XOR-pairing recv: partner = lane ^ M, all DPP (xor4..6 = two chained 1-cycle movs).
template <int M>
__device__ __forceinline__ float jrecv(float v) {
    if constexpr (M == 1) return fperm<0xB1>(v);
    else if constexpr (M == 2) return fperm<0x4E>(v);
    else if constexpr (M == 3) return fperm<0x1B>(v);
    else if constexpr (M == 7) return fperm<0x141>(v);
    else if constexpr (M == 4) return fperm<0x141>(fperm<0x1B>(v));
    else if constexpr (M == 5) return fperm<0x141>(fperm<0x4E>(v));
    else                       return fperm<0x141>(fperm<0xB1>(v));   // M == 6
}

// One Jacobi round with CARRIED squared norms: only the cross-dot z is computed
// (tree, depth ~4); norms update via xo' = c^2 xo + s^2 xr - 2cs z. tau from the
// local view gives opposite s / same c on partners => symmetric update.
template <int M>
__device__ __forceinline__ void jround(float (&o)[DIM], float& xo, bool& conv) {
    float r[DIM];
    #pragma unroll
    for (int k = 0; k < DIM; ++k) r[k] = jrecv<M>(o[k]);
    float xr = jrecv<M>(xo);
    float p0 = fmaf(o[1], r[1], o[0] * r[0]);
    float p1 = fmaf(o[3], r[3], o[2] * r[2]);
    float p2 = fmaf(o[5], r[5], o[4] * r[4]);
    float p3 = fmaf(o[7], r[7], o[6] * r[6]);
    float z  = (p0 + p1) + (p2 + p3);
    float z2 = z * z;
    float d  = xr - xo;
    if (z2 > 1.0e-12f * xo * xr && z2 > 1.0e-12f * d * d) conv = false;
    if (z2 > 1.0e-16f * xo * xr) {   // skip pure-noise rotations; guards rcp(0)
        float tau = d * (0.5f * __builtin_amdgcn_rcpf(z));
        float t = __builtin_amdgcn_rcpf(fabsf(tau) + sqrtf(fmaf(tau, tau, 1.0f)));
        t = (tau >= 0.0f) ? t : -t;
        float c = __builtin_amdgcn_rsqf(fmaf(t, t, 1.0f));
        float s = t * c;
        #pragma unroll
        for (int k = 0; k < DIM; ++k) o[k] = fmaf(c, o[k], -s * r[k]);
        float cc = c * c, ss = s * s, cs2 = 2.0f * c * s;
        xo = fmaf(cc, xo, fmaf(ss, xr, -cs2 * z));
    }
}

// 8 lanes per element: lane h owns G column h. All cross-lane via DPP (zero LDS).
__global__ void __launch_bounds__(256, 2)
qcbow_kernel(const int* __restrict__ contexts,  // [NB, SEQ]
             const int* __restrict__ targets,   // [NB]
             const float* __restrict__ emb,     // [100000, TRIL]
             float* __restrict__ out)           // [NB]
{
    const int tid = blockIdx.x * 256 + threadIdx.x;
    const int b = tid >> 3;
    const int h = threadIdx.x & 7;
    const bool q0 = (h < 4);

    // ---- token assignment: lane h -> ctx s=h; lanes 0,1 also ctx s=8,9; lanes 4-7 sigma
    const int base = b * SEQ;
    int tok1 = contexts[base + h];
    int tok2 = 0;                               // lanes 2,3: dummy row 0 (valid memory)
    if (h < 2)  tok2 = contexts[base + 8 + h];
    if (h >= 4) tok2 = targets[b];

    float F1[TRIL], F2[TRIL];                   // both rows loaded up-front (latency overlap)
    load_row(emb, tok1, F1);
    load_row(emb, tok2, F2);

    double A[TRIL];
    #pragma unroll
    for (int i = 0; i < TRIL; ++i) A[i] = 0.0;
    float cntf = 0.0f;

    if (tok1 != 0) { density_from<true>(F1, A); cntf = 1.0f; }
    double T[TRIL];                             // sigma on lanes 4-7; extra-ctx on lanes 0,1
    density_from<false>(F2, T);
    if (h < 2 && tok2 != 0) {
        #pragma unroll
        for (int i = 0; i < TRIL; ++i) A[i] += T[i];
        cntf += 1.0f;
    }

    // ---- allreduce A,cnt over octet: butterfly over xor generators {1,2,7}, all DPP ----
    #pragma unroll
    for (int i = 0; i < TRIL; ++i) A[i] += dperm<0xB1>(A[i]);
    cntf += fperm<0xB1>(cntf);
    #pragma unroll
    for (int i = 0; i < TRIL; ++i) A[i] += dperm<0x4E>(A[i]);
    cntf += fperm<0x4E>(cntf);
    #pragma unroll
    for (int i = 0; i < TRIL; ++i) A[i] += dperm<0x141>(A[i]);
    cntf += fperm<0x141>(cntf);

    double invc = rcp1((double)cntf);
    #pragma unroll
    for (int i = 0; i < TRIL; ++i) A[i] *= invc;
    #pragma unroll
    for (int d = 0; d < DIM; ++d) A[tri(d, d)] += 1.0e-6;   // rho_ctx + eps I = sqrt_rho^2

    // ---- ONE chol per lane: quad0 chols rho_ctx (A), quad1 chols sigma (T) ----
    double M[TRIL];
    #pragma unroll
    for (int i = 0; i < TRIL; ++i) M[i] = q0 ? A[i] : T[i];   // A,T die here
    chol36(M);

    // ---- w = Lw[:,h]: mirror pairing (lane h <-> 7-h). quad1 lane m muxes its own
    // column m and SENDS column 7-m so quad0 lane h receives exactly Lw[:,h].
    const bool h1 = (h & 1), h2 = (h & 2);
    double w[DIM];
    #pragma unroll
    for (int k = 0; k < DIM; ++k) {
        // E(J) = (k>=J) ? M[tri(k,J)] : 0 — folds at compile time per (k,J)
        #define E(J) ((k >= (J)) ? M[tri((k >= (J)) ? k : (J), (J))] : 0.0)
        double o0 = h1 ? E(5) : E(4);
        double o1 = h1 ? E(7) : E(6);
        double own = h2 ? o1 : o0;              // Lw[:,h]   (valid on quad1)
        double s0 = h1 ? E(2) : E(3);           // h2==0: h=4->3, h=5->2
        double s1 = h1 ? E(0) : E(1);           // h2==1: h=6->1, h=7->0
        double snd = h2 ? s1 : s0;              // Lw[:,7-h] (valid on quad1)
        #undef E
        double sw = dperm<0x141>(snd);          // quad0 lane h receives Lw[:,h]
        w[k] = q0 ? sw : own;
    }

    // ---- Lc broadcast quad0 -> quad1 via mirror (all quad0 lanes hold identical Lc) ----
    double Lx[TRIL];
    #pragma unroll
    for (int i = 0; i < TRIL; ++i) Lx[i] = dperm<0x141>(M[i]);
    double Lc[TRIL];
    #pragma unroll
    for (int i = 0; i < TRIL; ++i) Lc[i] = q0 ? M[i] : Lx[i];  // M,Lx die here

    // ---- G[:,h] = Lc^T * w ; eig((rho+epsI) sigma) = sing(G)^2 = final col norms^2
    float col[DIM];
    #pragma unroll
    for (int i = 0; i < DIM; ++i) {
        double s = 0.0;
        #pragma unroll
        for (int k = i; k < DIM; ++k) s += Lc[tri(k, i)] * w[k];  // w[k]=0 for k<h: W triangle
        col[i] = (float)s;
    }

    // ---- 8-processor one-sided Jacobi, XOR pairing: 7 rounds/sweep = all 28 pairs ----
    float q0n = fmaf(col[1], col[1], col[0] * col[0]);
    float q1n = fmaf(col[3], col[3], col[2] * col[2]);
    float q2n = fmaf(col[5], col[5], col[4] * col[4]);
    float q3n = fmaf(col[7], col[7], col[6] * col[6]);
    float xo = (q0n + q1n) + (q2n + q3n);       // carried squared norm
    for (int sweep = 0; sweep < 8; ++sweep) {
        bool conv = true;
        jround<1>(col, xo, conv);
        jround<2>(col, xo, conv);
        jround<3>(col, xo, conv);
        jround<4>(col, xo, conv);
        jround<5>(col, xo, conv);
        jround<6>(col, xo, conv);
        jround<7>(col, xo, conv);
        if (sweep >= 2 && __all(conv)) break;   // wave-uniform exit
    }

    // ---- lambda_h = ||col||^2 fresh in fp64 ; f = sum_h sqrt(lambda+1e-6) over octet ----
    double xn = 0.0;
    #pragma unroll
    for (int k = 0; k < DIM; ++k) xn += (double)col[k] * (double)col[k];
    double fp = sqrt1(xn + 1.0e-6);
    fp += dperm<0xB1>(fp);
    fp += dperm<0x4E>(fp);
    fp += dperm<0x141>(fp);
    if (h == 0) {
        double f = fmin(fp, 1.0);
        f = fmax(f, 1.0e-8);
        out[b] = (float)(-log(f));
    }
}

extern "C" void kernel_launch(void* const* d_in, const int* in_sizes, int n_in,
                              void* d_out, int out_size, void* d_ws, size_t ws_size,
                              hipStream_t stream) {
    const int*   contexts = (const int*)d_in[0];
    const int*   targets  = (const int*)d_in[1];
    const float* emb      = (const float*)d_in[2];
    float*       out      = (float*)d_out;

    qcbow_kernel<<<dim3(NB * 8 / 256), dim3(256), 0, stream>>>(contexts, targets, emb, out);
}